// Round 1
// baseline (199.656 us; speedup 1.0000x reference)
//
#include <hip/hip_runtime.h>
#include <math.h>

// Problem constants: B=2, L=768, H=256, NH=8, HD=32
#define NB 2
#define NL 768
#define NHID 256
#define NHEAD 8
#define DHEAD 32

// ---------------------------------------------------------------------------
// Generic fp32 tiled GEMM:  C[m,n] = alpha * sum_k A[m,k]*B(k,n) + bias[n]
// A row-major [M,lda].  BT=true: B is [N,K] row-major (B[n*ldb+k]);
// BT=false: B is [K,N] row-major (B[k*ldb+n]).  All dims divide tiles evenly.
// ---------------------------------------------------------------------------
template<int BM, int BN, int BK, int TM, int TN, bool BT>
__global__ __launch_bounds__(256) void gemm_f32(
    const float* __restrict__ A, int lda,
    const float* __restrict__ Bp, int ldb,
    const float* __restrict__ bias,
    float* __restrict__ C, int ldc,
    int M, int N, int K, float alpha)
{
    __shared__ float As[BK][BM + 4];
    __shared__ float Bs[BK][BN + 4];
    constexpr int TX = BN / TN;
    constexpr int TY = BM / TM;
    static_assert(TX * TY == 256, "block must be 256 threads");
    const int t = threadIdx.x;
    const int tx = t % TX, ty = t / TX;
    const int m0 = blockIdx.x * BM;
    const int n0 = blockIdx.y * BN;
    float acc[TM][TN] = {};
    for (int k0 = 0; k0 < K; k0 += BK) {
        for (int i = t; i < BM * BK; i += 256) {
            int r = i / BK, c = i % BK;
            As[c][r] = A[(size_t)(m0 + r) * lda + k0 + c];
        }
        if (BT) {
            for (int i = t; i < BN * BK; i += 256) {
                int r = i / BK, c = i % BK;
                Bs[c][r] = Bp[(size_t)(n0 + r) * ldb + k0 + c];
            }
        } else {
            for (int i = t; i < BK * BN; i += 256) {
                int r = i / BN, c = i % BN;
                Bs[r][c] = Bp[(size_t)(k0 + r) * ldb + n0 + c];
            }
        }
        __syncthreads();
        #pragma unroll
        for (int kk = 0; kk < BK; ++kk) {
            float a[TM], b[TN];
            #pragma unroll
            for (int i = 0; i < TM; ++i) a[i] = As[kk][ty * TM + i];
            #pragma unroll
            for (int j = 0; j < TN; ++j) b[j] = Bs[kk][tx * TN + j];
            #pragma unroll
            for (int i = 0; i < TM; ++i)
                #pragma unroll
                for (int j = 0; j < TN; ++j)
                    acc[i][j] = fmaf(a[i], b[j], acc[i][j]);
        }
        __syncthreads();
    }
    #pragma unroll
    for (int i = 0; i < TM; ++i) {
        int m = m0 + ty * TM + i;
        #pragma unroll
        for (int j = 0; j < TN; ++j) {
            int n = n0 + tx * TN + j;
            C[(size_t)m * ldc + n] = acc[i][j] * alpha + (bias ? bias[n] : 0.0f);
        }
    }
}

// ---------------------------------------------------------------------------
// scores[bh][m][n] = (1/sqrt(32)) * sum_d Q[b,m,h,d] * K[b,n,h,d]
// Q/K live inside qkv [B*L, 768] at column offsets 0 / 256.
// One block = 64x64 tile of one (b,h); K(=HD)=32 so a single LDS pass.
// ---------------------------------------------------------------------------
__global__ __launch_bounds__(256) void scores_kernel(
    const float* __restrict__ qkv, float* __restrict__ s)
{
    __shared__ float Qs[32][68];
    __shared__ float Ks[32][68];
    const int bh = blockIdx.z;
    const int b = bh >> 3, h = bh & 7;
    const int m0 = blockIdx.y * 64, n0 = blockIdx.x * 64;
    const int t = threadIdx.x;
    const float* qb = qkv + (size_t)b * NL * 768 + h * DHEAD;
    for (int u = t; u < 64 * 32; u += 256) {
        int r = u >> 5, c = u & 31;
        Qs[c][r] = qb[(size_t)(m0 + r) * 768 + c];
        Ks[c][r] = qb[(size_t)(n0 + r) * 768 + 256 + c];
    }
    __syncthreads();
    const int tx = t & 15, ty = t >> 4;
    float acc[4][4] = {};
    #pragma unroll
    for (int kk = 0; kk < 32; ++kk) {
        float4 a = *(const float4*)&Qs[kk][ty * 4];
        float4 bv = *(const float4*)&Ks[kk][tx * 4];
        acc[0][0] = fmaf(a.x, bv.x, acc[0][0]); acc[0][1] = fmaf(a.x, bv.y, acc[0][1]);
        acc[0][2] = fmaf(a.x, bv.z, acc[0][2]); acc[0][3] = fmaf(a.x, bv.w, acc[0][3]);
        acc[1][0] = fmaf(a.y, bv.x, acc[1][0]); acc[1][1] = fmaf(a.y, bv.y, acc[1][1]);
        acc[1][2] = fmaf(a.y, bv.z, acc[1][2]); acc[1][3] = fmaf(a.y, bv.w, acc[1][3]);
        acc[2][0] = fmaf(a.z, bv.x, acc[2][0]); acc[2][1] = fmaf(a.z, bv.y, acc[2][1]);
        acc[2][2] = fmaf(a.z, bv.z, acc[2][2]); acc[2][3] = fmaf(a.z, bv.w, acc[2][3]);
        acc[3][0] = fmaf(a.w, bv.x, acc[3][0]); acc[3][1] = fmaf(a.w, bv.y, acc[3][1]);
        acc[3][2] = fmaf(a.w, bv.z, acc[3][2]); acc[3][3] = fmaf(a.w, bv.w, acc[3][3]);
    }
    const float sc = 0.17677669529663687f; // 1/sqrt(32)
    float* sp = s + ((size_t)bh * NL + m0) * NL + n0;
    #pragma unroll
    for (int i = 0; i < 4; ++i)
        #pragma unroll
        for (int j = 0; j < 4; ++j)
            sp[(size_t)(ty * 4 + i) * NL + tx * 4 + j] = acc[i][j] * sc;
}

// ---------------------------------------------------------------------------
// In-place row softmax over 768 columns; one block per row.
// ---------------------------------------------------------------------------
__global__ __launch_bounds__(256) void softmax_rows(float* __restrict__ p)
{
    __shared__ float red[8];
    const int t = threadIdx.x;
    float* pr = p + (size_t)blockIdx.x * NL;
    float v[3];
    float m = -1e30f;
    #pragma unroll
    for (int i = 0; i < 3; ++i) { v[i] = pr[t + i * 256]; m = fmaxf(m, v[i]); }
    #pragma unroll
    for (int off = 32; off; off >>= 1) m = fmaxf(m, __shfl_xor(m, off));
    if ((t & 63) == 0) red[t >> 6] = m;
    __syncthreads();
    m = fmaxf(fmaxf(red[0], red[1]), fmaxf(red[2], red[3]));
    float ssum = 0.0f;
    #pragma unroll
    for (int i = 0; i < 3; ++i) { v[i] = __expf(v[i] - m); ssum += v[i]; }
    #pragma unroll
    for (int off = 32; off; off >>= 1) ssum += __shfl_xor(ssum, off);
    if ((t & 63) == 0) red[4 + (t >> 6)] = ssum;
    __syncthreads();
    const float inv = 1.0f / (red[4] + red[5] + red[6] + red[7]);
    #pragma unroll
    for (int i = 0; i < 3; ++i) pr[t + i * 256] = v[i] * inv;
}

// ---------------------------------------------------------------------------
// o[b,m,h*32+d] = sum_k P[bh][m][k] * V[b,k,h,d]   (V at qkv column 512)
// Block = 64 rows of one (b,h); thread computes 4 rows x 2 cols (d, d+16).
// ---------------------------------------------------------------------------
__global__ __launch_bounds__(256) void pv_kernel(
    const float* __restrict__ p, const float* __restrict__ qkv,
    float* __restrict__ o)
{
    __shared__ float Ps[64][68];
    __shared__ float Vt[32][68];   // Vt[d][k]
    const int bh = blockIdx.y;
    const int b = bh >> 3, h = bh & 7;
    const int m0 = blockIdx.x * 64;
    const int t = threadIdx.x;
    const int tx = t & 15, ty = t >> 4;
    const float* pb = p + ((size_t)bh * NL + m0) * NL;
    const float* vb = qkv + (size_t)b * NL * 768 + 512 + h * DHEAD;
    float acc[4][2] = {};
    for (int k0 = 0; k0 < NL; k0 += 64) {
        for (int u = t; u < 64 * 16; u += 256) {        // P tile as float4 units
            int r = u >> 4, c4 = u & 15;
            *(float4*)&Ps[r][c4 * 4] = *(const float4*)(pb + (size_t)r * NL + k0 + c4 * 4);
        }
        for (int u = t; u < 64 * 32; u += 256) {        // V tile, transposed store
            int r = u >> 5, c = u & 31;
            Vt[c][r] = vb[(size_t)(k0 + r) * 768 + c];
        }
        __syncthreads();
        #pragma unroll
        for (int kk4 = 0; kk4 < 16; ++kk4) {
            float4 v0 = *(const float4*)&Vt[tx][kk4 * 4];
            float4 v1 = *(const float4*)&Vt[tx + 16][kk4 * 4];
            #pragma unroll
            for (int i = 0; i < 4; ++i) {
                float4 pp = *(const float4*)&Ps[ty * 4 + i][kk4 * 4];
                acc[i][0] = fmaf(pp.x, v0.x, acc[i][0]);
                acc[i][0] = fmaf(pp.y, v0.y, acc[i][0]);
                acc[i][0] = fmaf(pp.z, v0.z, acc[i][0]);
                acc[i][0] = fmaf(pp.w, v0.w, acc[i][0]);
                acc[i][1] = fmaf(pp.x, v1.x, acc[i][1]);
                acc[i][1] = fmaf(pp.y, v1.y, acc[i][1]);
                acc[i][1] = fmaf(pp.z, v1.z, acc[i][1]);
                acc[i][1] = fmaf(pp.w, v1.w, acc[i][1]);
            }
        }
        __syncthreads();
    }
    float* ob = o + ((size_t)(b * NL + m0)) * NHID + h * DHEAD;
    #pragma unroll
    for (int i = 0; i < 4; ++i) {
        ob[(size_t)(ty * 4 + i) * NHID + tx] = acc[i][0];
        ob[(size_t)(ty * 4 + i) * NHID + tx + 16] = acc[i][1];
    }
}

// ---------------------------------------------------------------------------
// contact[b,i,j] = sum_c relu(row[b,i,c] + col[b,j,c]) * w2[c] + b2
// (b1 already folded into row via GEMM bias). 32x32 tile, 2x2 per thread.
// ---------------------------------------------------------------------------
__global__ __launch_bounds__(256) void pairwise_kernel(
    const float* __restrict__ rowm, const float* __restrict__ colm,
    const float* __restrict__ w2, const float* __restrict__ b2,
    float* __restrict__ out)
{
    __shared__ float rs[32][132];
    __shared__ float cs[32][132];
    __shared__ float w2s[128];
    const int b = blockIdx.z;
    const int i0 = blockIdx.y * 32;
    const int j0 = blockIdx.x * 32;
    const int t = threadIdx.x;
    for (int u = t; u < 32 * 32; u += 256) {   // float4 units of [32][128]
        int r = u >> 5, c4 = u & 31;
        *(float4*)&rs[r][c4 * 4] = *(const float4*)(rowm + (size_t)(b * NL + i0 + r) * 128 + c4 * 4);
        *(float4*)&cs[r][c4 * 4] = *(const float4*)(colm + (size_t)(b * NL + j0 + r) * 128 + c4 * 4);
    }
    if (t < 128) w2s[t] = w2[t];
    __syncthreads();
    const int tx = t & 15, ty = t >> 4;
    float a00 = 0.f, a01 = 0.f, a10 = 0.f, a11 = 0.f;
    #pragma unroll
    for (int c4 = 0; c4 < 32; ++c4) {
        float4 r0 = *(const float4*)&rs[ty][c4 * 4];
        float4 r1 = *(const float4*)&rs[ty + 16][c4 * 4];
        float4 c0 = *(const float4*)&cs[tx][c4 * 4];
        float4 c1 = *(const float4*)&cs[tx + 16][c4 * 4];
        float4 w = *(const float4*)&w2s[c4 * 4];
        a00 = fmaf(fmaxf(r0.x + c0.x, 0.f), w.x, a00);
        a00 = fmaf(fmaxf(r0.y + c0.y, 0.f), w.y, a00);
        a00 = fmaf(fmaxf(r0.z + c0.z, 0.f), w.z, a00);
        a00 = fmaf(fmaxf(r0.w + c0.w, 0.f), w.w, a00);
        a01 = fmaf(fmaxf(r0.x + c1.x, 0.f), w.x, a01);
        a01 = fmaf(fmaxf(r0.y + c1.y, 0.f), w.y, a01);
        a01 = fmaf(fmaxf(r0.z + c1.z, 0.f), w.z, a01);
        a01 = fmaf(fmaxf(r0.w + c1.w, 0.f), w.w, a01);
        a10 = fmaf(fmaxf(r1.x + c0.x, 0.f), w.x, a10);
        a10 = fmaf(fmaxf(r1.y + c0.y, 0.f), w.y, a10);
        a10 = fmaf(fmaxf(r1.z + c0.z, 0.f), w.z, a10);
        a10 = fmaf(fmaxf(r1.w + c0.w, 0.f), w.w, a10);
        a11 = fmaf(fmaxf(r1.x + c1.x, 0.f), w.x, a11);
        a11 = fmaf(fmaxf(r1.y + c1.y, 0.f), w.y, a11);
        a11 = fmaf(fmaxf(r1.z + c1.z, 0.f), w.z, a11);
        a11 = fmaf(fmaxf(r1.w + c1.w, 0.f), w.w, a11);
    }
    const float bb = b2[0];
    out[((size_t)b * NL + i0 + ty) * NL + j0 + tx]           = a00 + bb;
    out[((size_t)b * NL + i0 + ty) * NL + j0 + tx + 16]      = a01 + bb;
    out[((size_t)b * NL + i0 + ty + 16) * NL + j0 + tx]      = a10 + bb;
    out[((size_t)b * NL + i0 + ty + 16) * NL + j0 + tx + 16] = a11 + bb;
}

// ---------------------------------------------------------------------------
extern "C" void kernel_launch(void* const* d_in, const int* in_sizes, int n_in,
                              void* d_out, int out_size, void* d_ws, size_t ws_size,
                              hipStream_t stream)
{
    const float* features  = (const float*)d_in[0];  // [2,768,256]
    const float* in_proj_w = (const float*)d_in[1];  // [768,256]
    const float* in_proj_b = (const float*)d_in[2];  // [768]
    const float* out_w     = (const float*)d_in[3];  // [256,256]
    const float* out_b     = (const float*)d_in[4];  // [256]
    const float* w1        = (const float*)d_in[5];  // [512,128]
    const float* b1        = (const float*)d_in[6];  // [128]
    const float* w2        = (const float*)d_in[7];  // [128,1]
    const float* b2        = (const float*)d_in[8];  // [1]
    float* out = (float*)d_out;                      // [2,768,768]

    float* ws   = (float*)d_ws;
    float* qkv  = ws;                    // 1,179,648 floats [1536,768]
    float* sc   = qkv + 1179648;         // 9,437,184 floats [16,768,768]
    float* attn = sc + 9437184;          //   393,216 floats [1536,256]
    float* o2   = attn + 393216;         //   393,216 floats [1536,256]
    float* rowb = o2 + 393216;           //   196,608 floats [1536,128]
    float* colb = rowb + 196608;         //   196,608 floats [1536,128]

    // 1. qkv = features @ in_proj_w.T + in_proj_b     [1536,768]
    gemm_f32<64, 64, 16, 4, 4, true><<<dim3(24, 12), 256, 0, stream>>>(
        features, 256, in_proj_w, 256, in_proj_b, qkv, 768, 1536, 768, 256, 1.0f);

    // 2. scores = Q K^T / sqrt(32)                    [16,768,768]
    scores_kernel<<<dim3(12, 12, 16), 256, 0, stream>>>(qkv, sc);

    // 3. softmax rows (in place)
    softmax_rows<<<dim3(16 * 768), 256, 0, stream>>>(sc);

    // 4. attn = P V                                   [1536,256]
    pv_kernel<<<dim3(12, 16), 256, 0, stream>>>(sc, qkv, attn);

    // 5. o2 = attn @ out_w.T + out_b                  [1536,256]
    gemm_f32<32, 32, 32, 2, 2, true><<<dim3(48, 8), 256, 0, stream>>>(
        attn, 256, out_w, 256, out_b, o2, 256, 1536, 256, 256, 1.0f);

    // 6. row = o2 @ w1[:256] + b1                     [1536,128]
    gemm_f32<32, 32, 32, 2, 2, false><<<dim3(48, 4), 256, 0, stream>>>(
        o2, 256, w1, 128, b1, rowb, 128, 1536, 128, 256, 1.0f);

    // 7. col = o2 @ w1[256:]                          [1536,128]
    gemm_f32<32, 32, 32, 2, 2, false><<<dim3(48, 4), 256, 0, stream>>>(
        o2, 256, w1 + 256 * 128, 128, nullptr, colb, 128, 1536, 128, 256, 1.0f);

    // 8. contact map (fused pairwise MLP)             [2,768,768]
    pairwise_kernel<<<dim3(24, 24, 2), 256, 0, stream>>>(rowb, colb, w2, b2, out);
}

// Round 2
// 160.955 us; speedup vs baseline: 1.2404x; 1.2404x over previous
//
#include <hip/hip_runtime.h>
#include <math.h>

// Problem constants: B=2, L=768, H=256, NH=8, HD=32
#define NB 2
#define NL 768
#define NHID 256
#define NHEAD 8
#define DHEAD 32

// ---------------------------------------------------------------------------
// Generic fp32 tiled GEMM:  C[m,n] = sum_k A[m,k]*B(k,n) + bias[n]
// BT=true: B is [N,K] row-major; BT=false: B is [K,N] row-major.
// ---------------------------------------------------------------------------
template<int BM, int BN, int BK, int TM, int TN, bool BT>
__global__ __launch_bounds__(256) void gemm_f32(
    const float* __restrict__ A, int lda,
    const float* __restrict__ Bp, int ldb,
    const float* __restrict__ bias,
    float* __restrict__ C, int ldc,
    int M, int N, int K)
{
    __shared__ float As[BK][BM + 4];
    __shared__ float Bs[BK][BN + 4];
    constexpr int TX = BN / TN;
    constexpr int TY = BM / TM;
    static_assert(TX * TY == 256, "block must be 256 threads");
    const int t = threadIdx.x;
    const int tx = t % TX, ty = t / TX;
    const int m0 = blockIdx.x * BM;
    const int n0 = blockIdx.y * BN;
    float acc[TM][TN] = {};
    for (int k0 = 0; k0 < K; k0 += BK) {
        for (int i = t; i < BM * BK; i += 256) {
            int r = i / BK, c = i % BK;
            As[c][r] = A[(size_t)(m0 + r) * lda + k0 + c];
        }
        if (BT) {
            for (int i = t; i < BN * BK; i += 256) {
                int r = i / BK, c = i % BK;
                Bs[c][r] = Bp[(size_t)(n0 + r) * ldb + k0 + c];
            }
        } else {
            for (int i = t; i < BK * BN; i += 256) {
                int r = i / BN, c = i % BN;
                Bs[r][c] = Bp[(size_t)(k0 + r) * ldb + n0 + c];
            }
        }
        __syncthreads();
        #pragma unroll
        for (int kk = 0; kk < BK; ++kk) {
            float a[TM], b[TN];
            #pragma unroll
            for (int i = 0; i < TM; ++i) a[i] = As[kk][ty * TM + i];
            #pragma unroll
            for (int j = 0; j < TN; ++j) b[j] = Bs[kk][tx * TN + j];
            #pragma unroll
            for (int i = 0; i < TM; ++i)
                #pragma unroll
                for (int j = 0; j < TN; ++j)
                    acc[i][j] = fmaf(a[i], b[j], acc[i][j]);
        }
        __syncthreads();
    }
    #pragma unroll
    for (int i = 0; i < TM; ++i) {
        int m = m0 + ty * TM + i;
        #pragma unroll
        for (int j = 0; j < TN; ++j) {
            int n = n0 + tx * TN + j;
            C[(size_t)m * ldc + n] = acc[i][j] + (bias ? bias[n] : 0.0f);
        }
    }
}

// ---------------------------------------------------------------------------
// Fused flash attention: per block = 32 q-rows of one (b,h).
// qkv [1536,768]: Q at col h*32, K at 256+h*32, V at 512+h*32.
// Online softmax over k-tiles of 64. Output attn [1536,256].
// ---------------------------------------------------------------------------
__global__ __launch_bounds__(256) void attn_fused(
    const float* __restrict__ qkv, float* __restrict__ o)
{
    __shared__ float Qt[32][36];   // Qt[d][m], scaled by 1/sqrt(32)
    __shared__ float Kt[32][68];   // Kt[d][k]
    __shared__ float Vt[32][68];   // Vt[d][k]
    __shared__ float Ps[32][68];   // P[m][k]
    const int bh = blockIdx.y;
    const int b = bh >> 3, h = bh & 7;
    const int m0 = blockIdx.x * 32;
    const int t = threadIdx.x;
    const int tx = t & 15, ty = t >> 4;
    const float* base = qkv + (size_t)b * NL * 768;
    const float* qb = base + h * DHEAD;
    const float* kb = base + 256 + h * DHEAD;
    const float* vb = base + 512 + h * DHEAD;

    for (int u = t; u < 32 * 32; u += 256) {
        int m = u >> 5, d = u & 31;
        Qt[d][m] = qb[(size_t)(m0 + m) * 768 + d] * 0.17677669529663687f;
    }
    float m_run[2] = {-1e30f, -1e30f};
    float l_run[2] = {0.f, 0.f};
    float acc[2][2] = {};

    for (int k0 = 0; k0 < NL; k0 += 64) {
        __syncthreads();   // Kt/Vt WAR vs previous PV; also covers Qt on iter 0
        for (int u = t; u < 64 * 32; u += 256) {
            int kk = u >> 5, d = u & 31;
            Kt[d][kk] = kb[(size_t)(k0 + kk) * 768 + d];
            Vt[d][kk] = vb[(size_t)(k0 + kk) * 768 + d];
        }
        __syncthreads();

        // S tile 32x64: thread rows ty*2+{0,1}, cols tx*4+{0..3}
        float s[2][4] = {};
        #pragma unroll
        for (int d = 0; d < 32; ++d) {
            float2 a = *(const float2*)&Qt[d][ty * 2];
            float4 kv = *(const float4*)&Kt[d][tx * 4];
            s[0][0] = fmaf(a.x, kv.x, s[0][0]);
            s[0][1] = fmaf(a.x, kv.y, s[0][1]);
            s[0][2] = fmaf(a.x, kv.z, s[0][2]);
            s[0][3] = fmaf(a.x, kv.w, s[0][3]);
            s[1][0] = fmaf(a.y, kv.x, s[1][0]);
            s[1][1] = fmaf(a.y, kv.y, s[1][1]);
            s[1][2] = fmaf(a.y, kv.z, s[1][2]);
            s[1][3] = fmaf(a.y, kv.w, s[1][3]);
        }
        // online softmax per row (reduce across the 16 tx lanes of this ty)
        #pragma unroll
        for (int i = 0; i < 2; ++i) {
            float tmax = fmaxf(fmaxf(s[i][0], s[i][1]), fmaxf(s[i][2], s[i][3]));
            #pragma unroll
            for (int off = 8; off; off >>= 1) tmax = fmaxf(tmax, __shfl_xor(tmax, off));
            float m_new = fmaxf(m_run[i], tmax);
            float scale = __expf(m_run[i] - m_new);
            float p0 = __expf(s[i][0] - m_new);
            float p1 = __expf(s[i][1] - m_new);
            float p2 = __expf(s[i][2] - m_new);
            float p3 = __expf(s[i][3] - m_new);
            float tsum = p0 + p1 + p2 + p3;
            #pragma unroll
            for (int off = 8; off; off >>= 1) tsum += __shfl_xor(tsum, off);
            l_run[i] = l_run[i] * scale + tsum;
            m_run[i] = m_new;
            acc[i][0] *= scale;
            acc[i][1] *= scale;
            float4 pv = {p0, p1, p2, p3};
            *(float4*)&Ps[ty * 2 + i][tx * 4] = pv;
        }
        __syncthreads();

        // PV: thread rows ty*2+{0,1}, d cols tx and tx+16
        #pragma unroll
        for (int k4 = 0; k4 < 16; ++k4) {
            float4 v0 = *(const float4*)&Vt[tx][k4 * 4];
            float4 v1 = *(const float4*)&Vt[tx + 16][k4 * 4];
            #pragma unroll
            for (int i = 0; i < 2; ++i) {
                float4 p = *(const float4*)&Ps[ty * 2 + i][k4 * 4];
                acc[i][0] = fmaf(p.x, v0.x, acc[i][0]);
                acc[i][0] = fmaf(p.y, v0.y, acc[i][0]);
                acc[i][0] = fmaf(p.z, v0.z, acc[i][0]);
                acc[i][0] = fmaf(p.w, v0.w, acc[i][0]);
                acc[i][1] = fmaf(p.x, v1.x, acc[i][1]);
                acc[i][1] = fmaf(p.y, v1.y, acc[i][1]);
                acc[i][1] = fmaf(p.z, v1.z, acc[i][1]);
                acc[i][1] = fmaf(p.w, v1.w, acc[i][1]);
            }
        }
    }
    #pragma unroll
    for (int i = 0; i < 2; ++i) {
        float inv = 1.0f / l_run[i];
        float* ob = o + (size_t)(b * NL + m0 + ty * 2 + i) * NHID + h * DHEAD;
        ob[tx] = acc[i][0] * inv;
        ob[tx + 16] = acc[i][1] * inv;
    }
}

// ---------------------------------------------------------------------------
// Wc[k, c'] = sum_j out_w[j,k] * w1x[j, c'&127]  where w1x = w1 (c'<128) or
// w1+256*128 (c'>=128).  [256,256] output, grid (8,8), 32x32 tiles.
// ---------------------------------------------------------------------------
__global__ __launch_bounds__(256) void combine_w(
    const float* __restrict__ out_w, const float* __restrict__ w1,
    float* __restrict__ Wc)
{
    __shared__ float Aw[32][33];
    __shared__ float Bw[32][33];
    const int k0 = blockIdx.x * 32;
    const int c0 = blockIdx.y * 32;
    const float* w1x = w1 + (c0 >= 128 ? 256 * 128 : 0);
    const int cc0 = c0 & 127;
    const int t = threadIdx.x;
    const int tx = t & 15, ty = t >> 4;
    float acc[2][2] = {};
    for (int j0 = 0; j0 < 256; j0 += 32) {
        for (int u = t; u < 32 * 32; u += 256) {
            int r = u >> 5, c = u & 31;
            Aw[r][c] = out_w[(size_t)(j0 + r) * 256 + k0 + c];
            Bw[r][c] = w1x[(size_t)(j0 + r) * 128 + cc0 + c];
        }
        __syncthreads();
        #pragma unroll
        for (int jj = 0; jj < 32; ++jj) {
            float a0 = Aw[jj][ty * 2], a1 = Aw[jj][ty * 2 + 1];
            float b0 = Bw[jj][tx * 2], b1v = Bw[jj][tx * 2 + 1];
            acc[0][0] = fmaf(a0, b0, acc[0][0]);
            acc[0][1] = fmaf(a0, b1v, acc[0][1]);
            acc[1][0] = fmaf(a1, b0, acc[1][0]);
            acc[1][1] = fmaf(a1, b1v, acc[1][1]);
        }
        __syncthreads();
    }
    #pragma unroll
    for (int i = 0; i < 2; ++i)
        #pragma unroll
        for (int j = 0; j < 2; ++j)
            Wc[(size_t)(k0 + ty * 2 + i) * 256 + c0 + tx * 2 + j] = acc[i][j];
}

// bc[c'] = out_b . w1col(c')  (+ b1 for the row half)
__global__ __launch_bounds__(256) void combine_bias(
    const float* __restrict__ out_b, const float* __restrict__ w1,
    const float* __restrict__ b1, float* __restrict__ bc)
{
    const int t = threadIdx.x;
    const float* w1x = w1 + (t >= 128 ? 256 * 128 : 0);
    const int cc = t & 127;
    float a = 0.f;
    for (int j = 0; j < 256; ++j) a = fmaf(out_b[j], w1x[(size_t)j * 128 + cc], a);
    bc[t] = a + (t < 128 ? b1[cc] : 0.f);
}

// ---------------------------------------------------------------------------
// contact[b,i,j] = sum_c relu(row[b,i,c] + col[b,j,c]) * w2[c] + b2
// row = rowcol[:, 0:128], col = rowcol[:, 128:256] (b1 folded into row bias).
// ---------------------------------------------------------------------------
__global__ __launch_bounds__(256) void pairwise_kernel(
    const float* __restrict__ rowcol,
    const float* __restrict__ w2, const float* __restrict__ b2,
    float* __restrict__ out)
{
    __shared__ float rs[32][132];
    __shared__ float cs[32][132];
    __shared__ float w2s[128];
    const int b = blockIdx.z;
    const int i0 = blockIdx.y * 32;
    const int j0 = blockIdx.x * 32;
    const int t = threadIdx.x;
    for (int u = t; u < 32 * 32; u += 256) {   // float4 units of [32][128]
        int r = u >> 5, c4 = u & 31;
        *(float4*)&rs[r][c4 * 4] = *(const float4*)(rowcol + (size_t)(b * NL + i0 + r) * 256 + c4 * 4);
        *(float4*)&cs[r][c4 * 4] = *(const float4*)(rowcol + (size_t)(b * NL + j0 + r) * 256 + 128 + c4 * 4);
    }
    if (t < 128) w2s[t] = w2[t];
    __syncthreads();
    const int tx = t & 15, ty = t >> 4;
    float a00 = 0.f, a01 = 0.f, a10 = 0.f, a11 = 0.f;
    #pragma unroll
    for (int c4 = 0; c4 < 32; ++c4) {
        float4 r0 = *(const float4*)&rs[ty][c4 * 4];
        float4 r1 = *(const float4*)&rs[ty + 16][c4 * 4];
        float4 c0 = *(const float4*)&cs[tx][c4 * 4];
        float4 c1 = *(const float4*)&cs[tx + 16][c4 * 4];
        float4 w = *(const float4*)&w2s[c4 * 4];
        a00 = fmaf(fmaxf(r0.x + c0.x, 0.f), w.x, a00);
        a00 = fmaf(fmaxf(r0.y + c0.y, 0.f), w.y, a00);
        a00 = fmaf(fmaxf(r0.z + c0.z, 0.f), w.z, a00);
        a00 = fmaf(fmaxf(r0.w + c0.w, 0.f), w.w, a00);
        a01 = fmaf(fmaxf(r0.x + c1.x, 0.f), w.x, a01);
        a01 = fmaf(fmaxf(r0.y + c1.y, 0.f), w.y, a01);
        a01 = fmaf(fmaxf(r0.z + c1.z, 0.f), w.z, a01);
        a01 = fmaf(fmaxf(r0.w + c1.w, 0.f), w.w, a01);
        a10 = fmaf(fmaxf(r1.x + c0.x, 0.f), w.x, a10);
        a10 = fmaf(fmaxf(r1.y + c0.y, 0.f), w.y, a10);
        a10 = fmaf(fmaxf(r1.z + c0.z, 0.f), w.z, a10);
        a10 = fmaf(fmaxf(r1.w + c0.w, 0.f), w.w, a10);
        a11 = fmaf(fmaxf(r1.x + c1.x, 0.f), w.x, a11);
        a11 = fmaf(fmaxf(r1.y + c1.y, 0.f), w.y, a11);
        a11 = fmaf(fmaxf(r1.z + c1.z, 0.f), w.z, a11);
        a11 = fmaf(fmaxf(r1.w + c1.w, 0.f), w.w, a11);
    }
    const float bb = b2[0];
    out[((size_t)b * NL + i0 + ty) * NL + j0 + tx]           = a00 + bb;
    out[((size_t)b * NL + i0 + ty) * NL + j0 + tx + 16]      = a01 + bb;
    out[((size_t)b * NL + i0 + ty + 16) * NL + j0 + tx]      = a10 + bb;
    out[((size_t)b * NL + i0 + ty + 16) * NL + j0 + tx + 16] = a11 + bb;
}

// ---------------------------------------------------------------------------
extern "C" void kernel_launch(void* const* d_in, const int* in_sizes, int n_in,
                              void* d_out, int out_size, void* d_ws, size_t ws_size,
                              hipStream_t stream)
{
    const float* features  = (const float*)d_in[0];  // [2,768,256]
    const float* in_proj_w = (const float*)d_in[1];  // [768,256]
    const float* in_proj_b = (const float*)d_in[2];  // [768]
    const float* out_w     = (const float*)d_in[3];  // [256,256]
    const float* out_b     = (const float*)d_in[4];  // [256]
    const float* w1        = (const float*)d_in[5];  // [512,128]
    const float* b1        = (const float*)d_in[6];  // [128]
    const float* w2        = (const float*)d_in[7];  // [128,1]
    const float* b2        = (const float*)d_in[8];  // [1]
    float* out = (float*)d_out;                      // [2,768,768]

    float* ws     = (float*)d_ws;
    float* qkv    = ws;                      // [1536,768]
    float* attn   = qkv + 1179648;           // [1536,256]
    float* Wc     = attn + 393216;           // [256,256]
    float* bc     = Wc + 65536;              // [256]
    float* rowcol = bc + 256;                // [1536,256]

    // 0. combined weights (independent of activations)
    combine_w<<<dim3(8, 8), 256, 0, stream>>>(out_w, w1, Wc);
    combine_bias<<<1, 256, 0, stream>>>(out_b, w1, b1, bc);

    // 1. qkv = features @ in_proj_w.T + in_proj_b     [1536,768]
    gemm_f32<64, 64, 16, 4, 4, true><<<dim3(24, 12), 256, 0, stream>>>(
        features, 256, in_proj_w, 256, in_proj_b, qkv, 768, 1536, 768, 256);

    // 2. fused attention -> attn                      [1536,256]
    attn_fused<<<dim3(24, 16), 256, 0, stream>>>(qkv, attn);

    // 3. rowcol = attn @ Wc + bc                      [1536,256]
    gemm_f32<32, 32, 32, 2, 2, false><<<dim3(48, 8), 256, 0, stream>>>(
        attn, 256, Wc, 256, bc, rowcol, 256, 1536, 256, 256);

    // 4. contact map (fused pairwise MLP)             [2,768,768]
    pairwise_kernel<<<dim3(24, 24, 2), 256, 0, stream>>>(rowcol, w2, b2, out);
}

// Round 3
// 99.877 us; speedup vs baseline: 1.9990x; 1.6115x over previous
//
#include <hip/hip_runtime.h>
#include <math.h>

// Problem constants: B=2, L=768, H=256, NH=8, HD=32
#define NB 2
#define NL 768
#define NHID 256
#define NHEAD 8
#define DHEAD 32

typedef __attribute__((ext_vector_type(8))) short bf16x8;  // 8 bf16 = 4 VGPR
typedef __attribute__((ext_vector_type(4))) float f32x4;

__device__ __forceinline__ ushort f2bf(float f) {
    uint u = __float_as_uint(f);
    u += 0x7fffu + ((u >> 16) & 1u);           // round-to-nearest-even
    return (ushort)(u >> 16);
}
__device__ __forceinline__ uint pack2(float a, float b) {
    return (uint)f2bf(a) | ((uint)f2bf(b) << 16);
}
__device__ __forceinline__ uint4 pack8(float4 a, float4 b) {
    uint4 r;
    r.x = pack2(a.x, a.y); r.y = pack2(a.z, a.w);
    r.z = pack2(b.x, b.y); r.w = pack2(b.z, b.w);
    return r;
}
__device__ __forceinline__ float bflo(uint u) { return __uint_as_float(u << 16); }
__device__ __forceinline__ float bfhi(uint u) { return __uint_as_float(u & 0xffff0000u); }

// ---------------------------------------------------------------------------
// MFMA GEMM: C[m,n] = sum_k A[m,k] * Bt[n,k] + bias[n].
// A [M,K] (fp32 or bf16), Bt [N,K] (fp32 or bf16), out fp32 or bf16.
// BM=BN=64, BK=32, 4 waves, each wave 32x32 via 2x2 MFMA 16x16x32 tiles.
// ---------------------------------------------------------------------------
template<bool A_BF16, bool B_BF16, bool OUT_BF16>
__global__ __launch_bounds__(256) void gemm_mfma(
    const void* __restrict__ Ap, int lda,
    const void* __restrict__ Bp, int ldb,
    const float* __restrict__ bias,
    void* __restrict__ Cp, int ldc, int K)
{
    __shared__ __align__(16) ushort As[64 * 40];   // [row][k], pad 32->40
    __shared__ __align__(16) ushort Bs[64 * 40];   // [col][k]
    const int t = threadIdx.x;
    const int lane = t & 63, w = t >> 6;
    const int lg = lane >> 4, lc = lane & 15;
    const int wr = (w >> 1) * 32, wc = (w & 1) * 32;
    const int m0 = blockIdx.x * 64, n0 = blockIdx.y * 64;
    const int sr = t >> 2, sc = (t & 3) * 8;
    f32x4 acc[2][2] = {};
    for (int k0 = 0; k0 < K; k0 += 32) {
        __syncthreads();
        if (A_BF16) {
            *(uint4*)&As[sr * 40 + sc] =
                *(const uint4*)((const ushort*)Ap + (size_t)(m0 + sr) * lda + k0 + sc);
        } else {
            const float* ap = (const float*)Ap + (size_t)(m0 + sr) * lda + k0 + sc;
            *(uint4*)&As[sr * 40 + sc] = pack8(*(const float4*)ap, *(const float4*)(ap + 4));
        }
        if (B_BF16) {
            *(uint4*)&Bs[sr * 40 + sc] =
                *(const uint4*)((const ushort*)Bp + (size_t)(n0 + sr) * ldb + k0 + sc);
        } else {
            const float* bp = (const float*)Bp + (size_t)(n0 + sr) * ldb + k0 + sc;
            *(uint4*)&Bs[sr * 40 + sc] = pack8(*(const float4*)bp, *(const float4*)(bp + 4));
        }
        __syncthreads();
        bf16x8 a0 = *(const bf16x8*)&As[(wr + lc) * 40 + 8 * lg];
        bf16x8 a1 = *(const bf16x8*)&As[(wr + 16 + lc) * 40 + 8 * lg];
        bf16x8 b0 = *(const bf16x8*)&Bs[(wc + lc) * 40 + 8 * lg];
        bf16x8 b1 = *(const bf16x8*)&Bs[(wc + 16 + lc) * 40 + 8 * lg];
        acc[0][0] = __builtin_amdgcn_mfma_f32_16x16x32_bf16(a0, b0, acc[0][0], 0, 0, 0);
        acc[0][1] = __builtin_amdgcn_mfma_f32_16x16x32_bf16(a0, b1, acc[0][1], 0, 0, 0);
        acc[1][0] = __builtin_amdgcn_mfma_f32_16x16x32_bf16(a1, b0, acc[1][0], 0, 0, 0);
        acc[1][1] = __builtin_amdgcn_mfma_f32_16x16x32_bf16(a1, b1, acc[1][1], 0, 0, 0);
    }
    #pragma unroll
    for (int j = 0; j < 2; ++j) {
        int n = n0 + wc + 16 * j + lc;
        float bv = bias ? bias[n] : 0.f;
        #pragma unroll
        for (int i = 0; i < 2; ++i) {
            #pragma unroll
            for (int ii = 0; ii < 4; ++ii) {
                int m = m0 + wr + 16 * i + 4 * lg + ii;
                float v = acc[i][j][ii] + bv;
                if (OUT_BF16) ((ushort*)Cp)[(size_t)m * ldc + n] = f2bf(v);
                else          ((float*)Cp)[(size_t)m * ldc + n] = v;
            }
        }
    }
}

// ---------------------------------------------------------------------------
// MFMA flash attention. Block = 64 q-rows of one (b,h); 4 waves x 16 rows.
// qkv bf16 [1536,768]: Q at col h*32, K at 256+h*32, V at 512+h*32.
// Output attn bf16 [1536,256].
// ---------------------------------------------------------------------------
__global__ __launch_bounds__(256) void attn_mfma(
    const ushort* __restrict__ qkv, ushort* __restrict__ attn)
{
    __shared__ __align__(16) ushort Qs[64 * 40];       // [q-row][d]
    __shared__ __align__(16) ushort Ks[64 * 40];       // [k-row][d]
    __shared__ __align__(16) ushort Vt[32 * 72];       // [d][k-row]
    __shared__ __align__(16) ushort Ps[4 * 16 * 72];   // per-wave [q-row][k-col]
    const int bh = blockIdx.y, b = bh >> 3, h = bh & 7;
    const int m0 = blockIdx.x * 64;
    const int t = threadIdx.x, lane = t & 63, w = t >> 6;
    const int lg = lane >> 4, lc = lane & 15;
    const int sr = t >> 2, sc = (t & 3) * 8;
    ushort* Pw = Ps + w * (16 * 72);
    const float SC = 0.17677669529663687f;   // 1/sqrt(32)

    // stage Q (64 rows x 32 d) once
    *(uint4*)&Qs[sr * 40 + sc] =
        *(const uint4*)(qkv + (size_t)(b * NL + m0 + sr) * 768 + h * 32 + sc);

    f32x4 o0 = {}, o1 = {};
    float mr[4] = {-1e30f, -1e30f, -1e30f, -1e30f};
    float lr[4] = {0.f, 0.f, 0.f, 0.f};
    bf16x8 qa;

    for (int k0 = 0; k0 < NL; k0 += 64) {
        __syncthreads();   // prev-iter reads of Ks/Vt done; (iter0: Qs visible)
        *(uint4*)&Ks[sr * 40 + sc] =
            *(const uint4*)(qkv + (size_t)(b * NL + k0 + sr) * 768 + 256 + h * 32 + sc);
        {   // V staged transposed: Vt[d][k]
            uint4 vv = *(const uint4*)(qkv + (size_t)(b * NL + k0 + sr) * 768 + 512 + h * 32 + sc);
            uint vw[4] = {vv.x, vv.y, vv.z, vv.w};
            #pragma unroll
            for (int j = 0; j < 8; ++j)
                Vt[(sc + j) * 72 + sr] = (ushort)((vw[j >> 1] >> ((j & 1) * 16)) & 0xffffu);
        }
        __syncthreads();
        if (k0 == 0) qa = *(const bf16x8*)&Qs[(16 * w + lc) * 40 + 8 * lg];

        // S = Q K^T: 16x64 per wave, 4 MFMAs
        f32x4 s[4];
        #pragma unroll
        for (int t4 = 0; t4 < 4; ++t4) {
            bf16x8 kb = *(const bf16x8*)&Ks[(16 * t4 + lc) * 40 + 8 * lg];
            f32x4 z = {};
            s[t4] = __builtin_amdgcn_mfma_f32_16x16x32_bf16(qa, kb, z, 0, 0, 0);
        }
        // online softmax; C-layout: row = 4*lg+i (i=reg), col = 16*t4+lc
        #pragma unroll
        for (int i = 0; i < 4; ++i) {
            float mx = fmaxf(fmaxf(s[0][i], s[1][i]), fmaxf(s[2][i], s[3][i]));
            #pragma unroll
            for (int off = 1; off < 16; off <<= 1) mx = fmaxf(mx, __shfl_xor(mx, off));
            float mnew = fmaxf(mr[i], mx * SC);
            float resc = __expf(mr[i] - mnew);
            float tsum = 0.f;
            #pragma unroll
            for (int t4 = 0; t4 < 4; ++t4) {
                float p = __expf(s[t4][i] * SC - mnew);
                tsum += p;
                Pw[(4 * lg + i) * 72 + 16 * t4 + lc] = f2bf(p);
            }
            #pragma unroll
            for (int off = 1; off < 16; off <<= 1) tsum += __shfl_xor(tsum, off);
            mr[i] = mnew;
            lr[i] = lr[i] * resc + tsum;
            o0[i] *= resc;
            o1[i] *= resc;
        }
        // PV: O(16x32) += P(16x64) V(64x32); A=P frags, B from Vt
        bf16x8 pa0 = *(const bf16x8*)&Pw[lc * 72 + 8 * lg];
        bf16x8 pa1 = *(const bf16x8*)&Pw[lc * 72 + 32 + 8 * lg];
        bf16x8 v00 = *(const bf16x8*)&Vt[lc * 72 + 8 * lg];
        bf16x8 v10 = *(const bf16x8*)&Vt[lc * 72 + 32 + 8 * lg];
        bf16x8 v01 = *(const bf16x8*)&Vt[(16 + lc) * 72 + 8 * lg];
        bf16x8 v11 = *(const bf16x8*)&Vt[(16 + lc) * 72 + 32 + 8 * lg];
        o0 = __builtin_amdgcn_mfma_f32_16x16x32_bf16(pa0, v00, o0, 0, 0, 0);
        o0 = __builtin_amdgcn_mfma_f32_16x16x32_bf16(pa1, v10, o0, 0, 0, 0);
        o1 = __builtin_amdgcn_mfma_f32_16x16x32_bf16(pa0, v01, o1, 0, 0, 0);
        o1 = __builtin_amdgcn_mfma_f32_16x16x32_bf16(pa1, v11, o1, 0, 0, 0);
    }
    #pragma unroll
    for (int i = 0; i < 4; ++i) {
        float inv = 1.f / lr[i];
        size_t row = (size_t)(b * NL + m0 + 16 * w + 4 * lg + i);
        attn[row * 256 + h * 32 + lc]      = f2bf(o0[i] * inv);
        attn[row * 256 + h * 32 + 16 + lc] = f2bf(o1[i] * inv);
    }
}

// ---------------------------------------------------------------------------
// WcT[c',k] = sum_j out_w[j,k] * w1x[j, c'&127]  (bf16 out, transposed store)
// ---------------------------------------------------------------------------
__global__ __launch_bounds__(256) void combine_w(
    const float* __restrict__ out_w, const float* __restrict__ w1,
    ushort* __restrict__ WcT)
{
    __shared__ float Aw[32][33];
    __shared__ float Bw[32][33];
    const int k0 = blockIdx.x * 32;
    const int c0 = blockIdx.y * 32;
    const float* w1x = w1 + (c0 >= 128 ? 256 * 128 : 0);
    const int cc0 = c0 & 127;
    const int t = threadIdx.x;
    const int tx = t & 15, ty = t >> 4;
    float acc[2][2] = {};
    for (int j0 = 0; j0 < 256; j0 += 32) {
        for (int u = t; u < 32 * 32; u += 256) {
            int r = u >> 5, c = u & 31;
            Aw[r][c] = out_w[(size_t)(j0 + r) * 256 + k0 + c];
            Bw[r][c] = w1x[(size_t)(j0 + r) * 128 + cc0 + c];
        }
        __syncthreads();
        #pragma unroll
        for (int jj = 0; jj < 32; ++jj) {
            float a0 = Aw[jj][ty * 2], a1 = Aw[jj][ty * 2 + 1];
            float b0 = Bw[jj][tx * 2], b1v = Bw[jj][tx * 2 + 1];
            acc[0][0] = fmaf(a0, b0, acc[0][0]);
            acc[0][1] = fmaf(a0, b1v, acc[0][1]);
            acc[1][0] = fmaf(a1, b0, acc[1][0]);
            acc[1][1] = fmaf(a1, b1v, acc[1][1]);
        }
        __syncthreads();
    }
    #pragma unroll
    for (int i = 0; i < 2; ++i)
        #pragma unroll
        for (int j = 0; j < 2; ++j)
            WcT[(size_t)(c0 + tx * 2 + j) * 256 + (k0 + ty * 2 + i)] = f2bf(acc[i][j]);
}

// bc[c'] = out_b . w1col(c')  (+ b1 for the row half)
__global__ __launch_bounds__(256) void combine_bias(
    const float* __restrict__ out_b, const float* __restrict__ w1,
    const float* __restrict__ b1, float* __restrict__ bc)
{
    const int t = threadIdx.x;
    const float* w1x = w1 + (t >= 128 ? 256 * 128 : 0);
    const int cc = t & 127;
    float a0 = 0.f, a1 = 0.f, a2 = 0.f, a3 = 0.f;
    #pragma unroll 4
    for (int j = 0; j < 256; j += 4) {
        a0 = fmaf(out_b[j],     w1x[(size_t)j * 128 + cc],       a0);
        a1 = fmaf(out_b[j + 1], w1x[(size_t)(j + 1) * 128 + cc], a1);
        a2 = fmaf(out_b[j + 2], w1x[(size_t)(j + 2) * 128 + cc], a2);
        a3 = fmaf(out_b[j + 3], w1x[(size_t)(j + 3) * 128 + cc], a3);
    }
    bc[t] = (a0 + a1) + (a2 + a3) + (t < 128 ? b1[cc] : 0.f);
}

// ---------------------------------------------------------------------------
// contact[b,i,j] = sum_c relu(row[b,i,c] + col[b,j,c]) * w2[c] + b2
// rowcol fp32 [1536,256]: row half cols 0..127, col half 128..255.
// 64x64 tile, bf16 LDS, 4 waves (2x2), lane = (rg=lane>>3, cg=lane&7),
// per-lane 4x4 outputs at rows wr+rg+8i, cols wc+cg+8j (broadcast-friendly).
// ---------------------------------------------------------------------------
__global__ __launch_bounds__(256) void pairwise_kernel(
    const float* __restrict__ rowcol, const float* __restrict__ w2,
    const float* __restrict__ b2, float* __restrict__ out)
{
    __shared__ __align__(16) ushort rs[64 * 136];
    __shared__ __align__(16) ushort cs[64 * 136];
    __shared__ float w2s[128];
    const int b = blockIdx.z, i0 = blockIdx.y * 64, j0 = blockIdx.x * 64;
    const int t = threadIdx.x;
    const int sr = t >> 2, c32 = (t & 3) * 32;
    {
        const float* rp = rowcol + (size_t)(b * NL + i0 + sr) * 256 + c32;
        const float* cp = rowcol + (size_t)(b * NL + j0 + sr) * 256 + 128 + c32;
        #pragma unroll
        for (int q = 0; q < 4; ++q) {
            *(uint4*)&rs[sr * 136 + c32 + q * 8] =
                pack8(*(const float4*)(rp + q * 8), *(const float4*)(rp + q * 8 + 4));
            *(uint4*)&cs[sr * 136 + c32 + q * 8] =
                pack8(*(const float4*)(cp + q * 8), *(const float4*)(cp + q * 8 + 4));
        }
    }
    if (t < 128) w2s[t] = w2[t];
    __syncthreads();
    const int lane = t & 63, w = t >> 6;
    const int rg = lane >> 3, cg = lane & 7;
    const int wr = (w >> 1) * 32, wc = (w & 1) * 32;
    float acc[4][4] = {};
    for (int c8 = 0; c8 < 128; c8 += 8) {
        float wv[8];
        *(float4*)&wv[0] = *(const float4*)&w2s[c8];
        *(float4*)&wv[4] = *(const float4*)&w2s[c8 + 4];
        float rv[4][8], cv[4][8];
        #pragma unroll
        for (int i = 0; i < 4; ++i) {
            uint4 u = *(const uint4*)&rs[(wr + rg + 8 * i) * 136 + c8];
            rv[i][0] = bflo(u.x); rv[i][1] = bfhi(u.x);
            rv[i][2] = bflo(u.y); rv[i][3] = bfhi(u.y);
            rv[i][4] = bflo(u.z); rv[i][5] = bfhi(u.z);
            rv[i][6] = bflo(u.w); rv[i][7] = bfhi(u.w);
            uint4 v = *(const uint4*)&cs[(wc + cg + 8 * i) * 136 + c8];
            cv[i][0] = bflo(v.x); cv[i][1] = bfhi(v.x);
            cv[i][2] = bflo(v.y); cv[i][3] = bfhi(v.y);
            cv[i][4] = bflo(v.z); cv[i][5] = bfhi(v.z);
            cv[i][6] = bflo(v.w); cv[i][7] = bfhi(v.w);
        }
        #pragma unroll
        for (int i = 0; i < 4; ++i)
            #pragma unroll
            for (int j = 0; j < 4; ++j) {
                float a = acc[i][j];
                #pragma unroll
                for (int c = 0; c < 8; ++c)
                    a = fmaf(fmaxf(rv[i][c] + cv[j][c], 0.f), wv[c], a);
                acc[i][j] = a;
            }
    }
    const float bb = b2[0];
    #pragma unroll
    for (int i = 0; i < 4; ++i)
        #pragma unroll
        for (int j = 0; j < 4; ++j)
            out[(size_t)(b * NL + i0 + wr + rg + 8 * i) * NL + j0 + wc + cg + 8 * j] =
                acc[i][j] + bb;
}

// ---------------------------------------------------------------------------
extern "C" void kernel_launch(void* const* d_in, const int* in_sizes, int n_in,
                              void* d_out, int out_size, void* d_ws, size_t ws_size,
                              hipStream_t stream)
{
    const float* features  = (const float*)d_in[0];  // [2,768,256]
    const float* in_proj_w = (const float*)d_in[1];  // [768,256]
    const float* in_proj_b = (const float*)d_in[2];  // [768]
    const float* out_w     = (const float*)d_in[3];  // [256,256]
    const float* out_b     = (const float*)d_in[4];  // [256]
    const float* w1        = (const float*)d_in[5];  // [512,128]
    const float* b1        = (const float*)d_in[6];  // [128]
    const float* w2        = (const float*)d_in[7];  // [128,1]
    const float* b2        = (const float*)d_in[8];  // [1]
    float* out = (float*)d_out;                      // [2,768,768]

    ushort* qkvb   = (ushort*)d_ws;          // [1536,768] bf16
    ushort* attnb  = qkvb + 1179648;         // [1536,256] bf16
    ushort* WcT    = attnb + 393216;         // [256,256]  bf16 (transposed)
    float*  bc     = (float*)(WcT + 65536);  // [256]
    float*  rowcol = bc + 256;               // [1536,256] fp32

    // 0. combined weights (weights-only, tiny)
    combine_w<<<dim3(8, 8), 256, 0, stream>>>(out_w, w1, WcT);
    combine_bias<<<1, 256, 0, stream>>>(out_b, w1, b1, bc);

    // 1. qkv = features @ in_proj_w.T + in_proj_b   -> bf16 [1536,768]
    gemm_mfma<false, false, true><<<dim3(24, 12), 256, 0, stream>>>(
        features, 256, in_proj_w, 256, in_proj_b, qkvb, 768, 256);

    // 2. fused MFMA flash attention -> attn bf16 [1536,256]
    attn_mfma<<<dim3(12, 16), 256, 0, stream>>>(qkvb, attnb);

    // 3. rowcol = attn @ Wc + bc  -> fp32 [1536,256]
    gemm_mfma<true, true, false><<<dim3(24, 4), 256, 0, stream>>>(
        attnb, 256, WcT, 256, bc, rowcol, 256, 256);

    // 4. contact map (fused pairwise MLP) -> fp32 [2,768,768]
    pairwise_kernel<<<dim3(12, 12, 2), 256, 0, stream>>>(rowcol, w2, b2, out);
}